// Round 15
// baseline (235.319 us; speedup 1.0000x reference)
//
#include <hip/hip_runtime.h>
#include <hip/hip_fp16.h>

// GCN: h1 = relu(Agg(x@W1)+b1); h2 = relu(Agg(h1@W2)+b2); out = mean(h2)@Wc+bc
// norm(r,c)=dinv[r]*dinv[c] factors: GEMM epilogue prescales rows by dinv[r],
// agg sums rows, scales by dinv[c] at the end.
// R1: agg MLP. R2-R4: scattered atomics/fences = fixed-rate memory-side
//     resource — avoid. R5-R8: zero-atomic CSR build + fusion. R9: MFMA gemms.
// R10: rank-at-count parallel scatter (230). R11: more ILP NEUTRAL.
// R12: fp8 gather rows (aggs ~15-20us each). R13: tail fence revert (212).
// R14: aggs are EA-path bound: hs8 (6.4MB) > 4MB per-XCD L2 => gathers miss
//      L2 (R6 evidence: FETCH ~= logical traffic). Split hs8 into two 3.2MB
//      column PLANES (cols 0-63 / 64-127); agg block = 4 nodes x 1 plane,
//      plane = blockIdx&7 >= 4 (round-robin XCD heuristic) => per-XCD gather
//      working set fits L2.

typedef _Float16 half8 __attribute__((ext_vector_type(8)));
typedef float f32x4 __attribute__((ext_vector_type(4)));
typedef float f32x2 __attribute__((ext_vector_type(2)));

constexpr int N = 50000;
constexpr int E = 800000;
constexpr int D = 128;
constexpr int DOUT = 40;
constexpr int CAP = 64;               // slots/node (Poisson(16) tail ~1e-18)
constexpr int HB = 128;               // histogram chunks
constexpr int EPB = E / HB;           // 6250 edges/chunk
constexpr int HWRD = 12500;           // 50000 bytes = 12500 words
constexpr int GM = (N + 127) / 128;   // 391 gemm blocks
constexpr int NQ = N / 4;             // 12500 node quads
constexpr int GA = NQ * 2;            // 25000 agg blocks (quad x plane)
constexpr int T4 = E / 4;             // 200000 scatter threads
constexpr int GF = 3 * GM;            // 1173 = 782 scatter + 391 gemm
constexpr int PSTRIDE = N * 64;       // plane stride in bytes

// ---------------- Phase A: chunk histograms + per-edge rank + W transpose ---
__global__ __launch_bounds__(1024) void k_hist(const int* __restrict__ col,
                                               unsigned char* __restrict__ hist,
                                               unsigned char* __restrict__ rank,
                                               const float* __restrict__ W1,
                                               const float* __restrict__ W2,
                                               __half* __restrict__ T1,
                                               __half* __restrict__ T2) {
    __shared__ unsigned int h[HWRD];
    int b = blockIdx.x, t = threadIdx.x;
    if (b >= HB) {                        // 32 spare blocks: Wt[n][k]=fp16(W[k][n])
        int o = (b - HB) * 1024 + t;      // 0..32767
        const float* W = (o < 16384) ? W1 : W2;
        __half* T = (o < 16384) ? T1 : T2;
        int oo = o & 16383;
        int n = oo >> 7, k = oo & 127;
        T[oo] = (__half)W[k * 128 + n];
        return;
    }
    for (int i = t; i < HWRD; i += 1024) h[i] = 0;
    __syncthreads();
    int e0 = b * EPB;
    for (int e = e0 + t; e < e0 + EPB; e += 1024) {
        int c = col[e];
        unsigned int old = atomicAdd(&h[c >> 2], 1u << ((c & 3) * 8));
        rank[e] = (unsigned char)((old >> ((c & 3) * 8)) & 0xff);
    }
    __syncthreads();
    unsigned int* out = (unsigned int*)(hist + (size_t)b * 50000);
    for (int i = t; i < HWRD; i += 1024) out[i] = h[i];
}

// ---------------- Phase B: per-node prefix over chunks; deg + dinv ---------
__global__ void k_colscan(unsigned char* __restrict__ hist, int* __restrict__ deg,
                          float* __restrict__ dinv) {
    int c = blockIdx.x * 256 + threadIdx.x;
    if (c >= N) return;
    int sum = 0;
#pragma unroll 4
    for (int b = 0; b < HB; ++b) {
        size_t idx = (size_t)b * 50000 + c;
        int v = hist[idx];
        hist[idx] = (unsigned char)sum;   // exclusive prefix (deg<=255)
        sum += v;
    }
    deg[c] = sum;
    dinv[c] = rsqrtf((float)(sum + 1));   // +1 self loop
}

// ---------------- fp8 helpers (OCP e4m3 on gfx950) ----------------
__device__ __forceinline__ unsigned char f8enc(float v) {
    return (unsigned char)(__builtin_amdgcn_cvt_pk_fp8_f32(v, v, 0, false) & 0xff);
}
__device__ __forceinline__ void add8f8(float* a, uint2 u) {
    f32x2 f0 = __builtin_amdgcn_cvt_pk_f32_fp8(u.x, false);
    f32x2 f1 = __builtin_amdgcn_cvt_pk_f32_fp8(u.x, true);
    f32x2 f2 = __builtin_amdgcn_cvt_pk_f32_fp8(u.y, false);
    f32x2 f3 = __builtin_amdgcn_cvt_pk_f32_fp8(u.y, true);
    a[0] += f0[0]; a[1] += f0[1]; a[2] += f1[0]; a[3] += f1[1];
    a[4] += f2[0]; a[5] += f2[1]; a[6] += f3[0]; a[7] += f3[1];
}

// ---------------- MFMA GEMM: out8 planes = fp8(dinv[r] * (A[r] @ W)) -------
// out8 layout: plane p (cols p*64..p*64+63) at out8 + p*PSTRIDE, row r at +r*64.
__device__ __forceinline__ half8 ldA(const float* rowp, int koff) {
    float4 u0 = *(const float4*)(rowp + koff);
    float4 u1 = *(const float4*)(rowp + koff + 4);
    half8 r;
    r[0] = (_Float16)u0.x; r[1] = (_Float16)u0.y;
    r[2] = (_Float16)u0.z; r[3] = (_Float16)u0.w;
    r[4] = (_Float16)u1.x; r[5] = (_Float16)u1.y;
    r[6] = (_Float16)u1.z; r[7] = (_Float16)u1.w;
    return r;
}
__device__ __forceinline__ half8 ldA(const __half* rowp, int koff) {
    return *(const half8*)(rowp + koff);
}

template <typename TA>
__device__ __forceinline__ void mfma_gemm(const TA* __restrict__ A,
                                          const __half* __restrict__ Wt,
                                          const float* __restrict__ dinv,
                                          unsigned char* __restrict__ out8,
                                          int row0, int tid) {
    int wave = tid >> 6, lane = tid & 63;
    int quad = lane >> 4, c16 = lane & 15;
    int m0 = row0 + wave * 32;
    int ra = m0 + c16;      if (ra >= N) ra = 0;   // OOB rows: dummy read row 0
    int rb = m0 + 16 + c16; if (rb >= N) rb = 0;
    const TA* pa = A + (size_t)ra * D;
    const TA* pb = A + (size_t)rb * D;

    f32x4 acc[2][8];
#pragma unroll
    for (int i = 0; i < 2; ++i)
#pragma unroll
        for (int j = 0; j < 8; ++j) acc[i][j] = (f32x4){0.f, 0.f, 0.f, 0.f};

#pragma unroll
    for (int kq = 0; kq < 4; ++kq) {
        int koff = kq * 32 + quad * 8;
        half8 a0 = ldA(pa, koff);
        half8 a1 = ldA(pb, koff);
#pragma unroll
        for (int nt = 0; nt < 8; ++nt) {
            half8 bf = *(const half8*)(Wt + (size_t)(nt * 16 + c16) * D + koff);
            acc[0][nt] = __builtin_amdgcn_mfma_f32_16x16x32_f16(a0, bf, acc[0][nt], 0, 0, 0);
            acc[1][nt] = __builtin_amdgcn_mfma_f32_16x16x32_f16(a1, bf, acc[1][nt], 0, 0, 0);
        }
    }

    // C/D: col = lane&15, row = quad*4 + reg. Plane-split byte stores.
#pragma unroll
    for (int rt = 0; rt < 2; ++rt) {
        int mt = m0 + rt * 16;
#pragma unroll
        for (int i = 0; i < 4; ++i) {
            int grow = mt + quad * 4 + i;
            if (grow < N) {
                float s = dinv[grow];
                unsigned char* o0 = out8 + (size_t)grow * 64 + c16;
                unsigned char* o1 = o0 + PSTRIDE;
#pragma unroll
                for (int nt = 0; nt < 4; ++nt) {
                    o0[nt * 16] = f8enc(acc[rt][nt][i] * s);
                    o1[nt * 16] = f8enc(acc[rt][nt + 4][i] * s);
                }
            }
        }
    }
}

// ---------------- Phase C fused: parallel rank-scatter + GEMM-1 -------------
__global__ __launch_bounds__(256) void k_fuse(const int* __restrict__ ei,
                                              const unsigned char* __restrict__ hist,
                                              const unsigned char* __restrict__ rank,
                                              unsigned short* __restrict__ csr,
                                              const float* __restrict__ x,
                                              const __half* __restrict__ Wt1,
                                              const float* __restrict__ dinv,
                                              unsigned char* __restrict__ out8) {
    int b = blockIdx.x, m = b % 3;
    if (m < 2) {
        // ---- scatter: fully parallel, slot = pref[chunk][c] + rank[e] ----
        int sb = (b / 3) * 2 + m;
        int t = sb * 256 + threadIdx.x;
        if (t >= T4) return;
#pragma unroll
        for (int i = 0; i < 4; ++i) {
            int e = t + i * T4;
            int c = ei[E + e];
            int r = ei[e];
            int chunk = e / EPB;
            int slot = (int)hist[(size_t)chunk * 50000 + c] + (int)rank[e];
            if (slot < CAP) csr[(c << 6) + slot] = (unsigned short)r;
        }
        return;
    }
    // ---- gemm branch ----
    mfma_gemm<float>(x, Wt1, dinv, out8, (b / 3) * 128, threadIdx.x);
}

// ---------------- GEMM layer 2 (fp16 A -> fp8 planes) ----------------
__global__ __launch_bounds__(256) void k_gemm(const __half* __restrict__ A,
                                              const __half* __restrict__ Wt,
                                              const float* __restrict__ dinv,
                                              unsigned char* __restrict__ out8) {
    mfma_gemm<__half>(A, Wt, dinv, out8, blockIdx.x * 128, threadIdx.x);
}

// ---------------- Aggregation core (1 wave/node/plane, fp8 row-sum) --------
// lane = g*8+q8: group g in [0,8) = edge slot, q8 in [0,8) = 8-byte column.
// hs8p = plane base; row c at hs8p + c*64. Result a[8] valid in all lanes.
__device__ __forceinline__ float agg_core(int c, int lane,
                                          const unsigned char* __restrict__ hs8p,
                                          const int* __restrict__ deg,
                                          const unsigned short* __restrict__ csr,
                                          float* a0) {
    int g  = lane >> 3;        // 0..7: edge within group of 8
    int q8 = lane & 7;         // column group: bytes q8*8..q8*8+7
    int dgRaw = deg[c];
    int dg = dgRaw < CAP ? dgRaw : CAP;
    float dc = rsqrtf((float)(dgRaw + 1));
    int e0 = c << 6;

    float a1[8] = {0, 0, 0, 0, 0, 0, 0, 0};
#pragma unroll
    for (int t = 0; t < 8; ++t) a0[t] = 0.f;
    if (g == 0)                 // self loop (hs8 row already = dinv[c]*h[c])
        add8f8(a0, *(const uint2*)&hs8p[(size_t)c * 64 + q8 * 8]);

    int j = 0;
    for (; j + 16 <= dg; j += 16) {       // 16 edges/iter, 2 loads in flight
        int r0 = csr[e0 + j + g];
        int r1 = csr[e0 + j + 8 + g];
        uint2 u0 = *(const uint2*)&hs8p[(size_t)r0 * 64 + q8 * 8];
        uint2 u1 = *(const uint2*)&hs8p[(size_t)r1 * 64 + q8 * 8];
        add8f8(a0, u0); add8f8(a1, u1);
    }
    if (j + 8 <= dg) {
        int r0 = csr[e0 + j + g];
        add8f8(a0, *(const uint2*)&hs8p[(size_t)r0 * 64 + q8 * 8]);
        j += 8;
    }
    int rem = dg - j;                     // 0..7
    if (g < rem) {
        int r0 = csr[e0 + j + g];
        add8f8(a1, *(const uint2*)&hs8p[(size_t)r0 * 64 + q8 * 8]);
    }

#pragma unroll
    for (int t = 0; t < 8; ++t) a0[t] += a1[t];
#pragma unroll
    for (int t = 0; t < 8; ++t) a0[t] += __shfl_xor(a0[t], 8, 64);
#pragma unroll
    for (int t = 0; t < 8; ++t) a0[t] += __shfl_xor(a0[t], 16, 64);
#pragma unroll
    for (int t = 0; t < 8; ++t) a0[t] += __shfl_xor(a0[t], 32, 64);
    return dc;
}

// block decode: b -> (quad, plane). plane from blockIdx&7 (XCD round-robin).
__device__ __forceinline__ void agg_idx(int b, int& quad, int& p) {
    p = ((b & 7) >> 2);
    quad = (b >> 3) * 4 + (b & 3);
}

// layer-1 agg: writes fp16 half-rows of hact (gemm2 input)
__global__ __launch_bounds__(256) void k_agg1(const unsigned char* __restrict__ hs8,
                                              const int* __restrict__ deg,
                                              const unsigned short* __restrict__ csr,
                                              const float* __restrict__ bias,
                                              __half* __restrict__ outH) {
    int quad, p;
    agg_idx(blockIdx.x, quad, p);
    int wave = threadIdx.x >> 6;
    int lane = threadIdx.x & 63;
    int c = quad * 4 + wave;
    const unsigned char* hs8p = hs8 + (size_t)p * PSTRIDE;
    float a0[8];
    float dc = agg_core(c, lane, hs8p, deg, csr, a0);
    if ((lane >> 3) == 0) {
        int q8 = lane & 7;
        int cb = p * 64 + q8 * 8;          // column base in the full 128-row
        union { __half2 h[4]; uint4 u; } pk;
#pragma unroll
        for (int i = 0; i < 4; ++i) {
            float xv = fmaxf(fmaf(dc, a0[2 * i],     bias[cb + 2 * i]),     0.f);
            float yv = fmaxf(fmaf(dc, a0[2 * i + 1], bias[cb + 2 * i + 1]), 0.f);
            pk.h[i] = __floats2half2_rn(xv, yv);
        }
        *(uint4*)&outH[(size_t)c * D + cb] = pk.u;
    }
}

// layer-2 agg: reduces straight into per-quad pool partials (64-col half)
__global__ __launch_bounds__(256) void k_agg2(const unsigned char* __restrict__ hs8,
                                              const int* __restrict__ deg,
                                              const unsigned short* __restrict__ csr,
                                              const float* __restrict__ bias,
                                              float* __restrict__ gpart) {
    __shared__ float gblk[4][64];
    int quad, p;
    agg_idx(blockIdx.x, quad, p);
    int wave = threadIdx.x >> 6;
    int lane = threadIdx.x & 63;
    int c = quad * 4 + wave;
    const unsigned char* hs8p = hs8 + (size_t)p * PSTRIDE;
    float a0[8];
    float dc = agg_core(c, lane, hs8p, deg, csr, a0);
    if ((lane >> 3) == 0) {
        int q8 = lane & 7;
        int cb = p * 64 + q8 * 8;
#pragma unroll
        for (int i = 0; i < 8; ++i)
            gblk[wave][q8 * 8 + i] = fmaxf(fmaf(dc, a0[i], bias[cb + i]), 0.f);
    }
    __syncthreads();
    int t = threadIdx.x;
    if (t < 64)
        gpart[(size_t)quad * 128 + p * 64 + t] =
            gblk[0][t] + gblk[1][t] + gblk[2][t] + gblk[3][t];
}

// ---------------- Pool stage 2: 12500 partials -> 256 partials --------------
__global__ __launch_bounds__(256) void k_pool(const float* __restrict__ gpart,
                                              float* __restrict__ gpart2) {
    int d = threadIdx.x & 127;
    int half = threadIdx.x >> 7;
    int b = blockIdx.x;                 // 256 blocks
    int per = (NQ + 255) / 256;         // 49
    int r0 = b * per;
    int r1 = r0 + per;
    if (r1 > NQ) r1 = NQ;
    float acc = 0.f;
    for (int r = r0 + half; r < r1; r += 2)
        acc += gpart[(size_t)r * D + d];
    __shared__ float red[256];
    red[threadIdx.x] = acc;
    __syncthreads();
    if (half == 0) gpart2[(size_t)b * D + d] = red[d] + red[128 + d];
}

// ---------------- Final: g = sum(gpart2)/N; out = g@Wc + bc ----------------
__global__ __launch_bounds__(512) void k_final(const float* __restrict__ gpart2,
                                               const float* __restrict__ Wc,
                                               const float* __restrict__ bc,
                                               float* __restrict__ out) {
    __shared__ float g[D];
    __shared__ float red[512];
    int t = threadIdx.x;
    int d = t & 127, grp = t >> 7;
    float s = 0.f;
#pragma unroll 4
    for (int w = grp * 64; w < grp * 64 + 64; ++w)
        s += gpart2[(size_t)w * D + d];
    red[t] = s;
    __syncthreads();
    if (grp == 0)
        g[d] = (red[d] + red[128 + d] + red[256 + d] + red[384 + d]) * (1.0f / (float)N);
    __syncthreads();
    if (t < DOUT) {
        float acc = bc[t];
        for (int dd = 0; dd < D; ++dd) acc = fmaf(g[dd], Wc[dd * DOUT + t], acc);
        out[t] = acc;
    }
}

extern "C" void kernel_launch(void* const* d_in, const int* in_sizes, int n_in,
                              void* d_out, int out_size, void* d_ws, size_t ws_size,
                              hipStream_t stream) {
    const float* x  = (const float*)d_in[0];
    const int*   ei = (const int*)d_in[1];
    const float* W1 = (const float*)d_in[2];
    const float* b1 = (const float*)d_in[3];
    const float* W2 = (const float*)d_in[4];
    const float* b2 = (const float*)d_in[5];
    const float* Wc = (const float*)d_in[6];
    const float* bc = (const float*)d_in[7];
    float* out = (float*)d_out;

    char* ws = (char*)d_ws;
    size_t off = 0;
    auto alloc = [&](size_t bytes) {
        void* p = ws + off;
        off += (bytes + 511) & ~(size_t)511;
        return p;
    };
    unsigned char*  hist   = (unsigned char*) alloc((size_t)HB * 50000);     // 6.4MB
    unsigned char*  rank   = (unsigned char*) alloc((size_t)E);              // 0.8MB
    int*            deg    = (int*)           alloc((size_t)N * 4);
    float*          dinv   = (float*)         alloc((size_t)N * 4);
    unsigned short* csr    = (unsigned short*)alloc((size_t)N * CAP * 2);    // 6.4MB
    unsigned char*  hs8    = (unsigned char*) alloc((size_t)N * D);          // 6.4MB (2 planes)
    __half*         hactH  = (__half*)        alloc((size_t)N * D * 2);      // 12.8MB
    __half*         Wt1    = (__half*)        alloc((size_t)D * D * 2);      // 32KB
    __half*         Wt2    = (__half*)        alloc((size_t)D * D * 2);      // 32KB
    float*          gpart  = (float*)         alloc((size_t)NQ * D * 4);     // 6.4MB
    float*          gpart2 = (float*)         alloc((size_t)256 * D * 4);
    (void)ws_size; (void)in_sizes; (void)n_in; (void)out_size;

    const int* col = ei + E;

    // Phase A: histograms + ranks + W transposes (one dispatch)
    k_hist<<<HB + 32, 1024, 0, stream>>>(col, hist, rank, W1, W2, Wt1, Wt2);
    // Phase B: per-node prefix; deg/dinv
    k_colscan<<<(N + 255) / 256, 256, 0, stream>>>(hist, deg, dinv);
    // Phase C: parallel scatter (2/3) + MFMA gemm layer 1 (1/3) -> fp8 planes
    k_fuse<<<GF, 256, 0, stream>>>(ei, hist, rank, csr, x, Wt1, dinv, hs8);

    k_agg1<<<GA, 256, 0, stream>>>(hs8, deg, csr, b1, hactH);
    k_gemm<<<GM, 256, 0, stream>>>(hactH, Wt2, dinv, hs8);
    k_agg2<<<GA, 256, 0, stream>>>(hs8, deg, csr, b2, gpart);
    k_pool<<<256, 256, 0, stream>>>(gpart, gpart2);
    k_final<<<1, 512, 0, stream>>>(gpart2, Wc, bc, out);
}

// Round 16
// 214.660 us; speedup vs baseline: 1.0962x; 1.0962x over previous
//
#include <hip/hip_runtime.h>
#include <hip/hip_fp16.h>

// GCN: h1 = relu(Agg(x@W1)+b1); h2 = relu(Agg(h1@W2)+b2); out = mean(h2)@Wc+bc
// norm(r,c)=dinv[r]*dinv[c] factors: GEMM epilogue prescales rows by dinv[r],
// agg sums rows, scales by dinv[c] at the end.
// R1: agg MLP. R2-R4: scattered atomics/fences = fixed-rate memory-side
//     resource (~14-16 G ops/s, invariant to ILP/contention/scope) — avoid.
// R5-R8: zero-atomic CSR build + scatter/gemm fusion. R9: MFMA fp16 gemms.
// R10: rank-at-count parallel scatter (230). R11: more agg ILP NEUTRAL
//     (throughput-bound). R12: fp8 e4m3 gather rows. R13: split tail,
//     no fences (212 — best).
// R14: plane-split XCD-affine gather — FETCH 93->23MB (L2 locality REAL) but
//     REGRESSED to 235: per-wave useful work halved (2 loads/lane) so fixed
//     per-node overhead (~100 instrs: reduction+epilogue) dominated,
//     VALUBusy 57%. Reverted to R13: 4 loads/lane amortizes overhead; both
//     directions (more/fewer lanes per edge) now empirically falsified.

typedef _Float16 half8 __attribute__((ext_vector_type(8)));
typedef float f32x4 __attribute__((ext_vector_type(4)));
typedef float f32x2 __attribute__((ext_vector_type(2)));

constexpr int N = 50000;
constexpr int E = 800000;
constexpr int D = 128;
constexpr int DOUT = 40;
constexpr int CAP = 64;               // slots/node (Poisson(16) tail ~1e-18)
constexpr int HB = 128;               // histogram chunks
constexpr int EPB = E / HB;           // 6250 edges/chunk
constexpr int HWRD = 12500;           // 50000 bytes = 12500 words
constexpr int GM = (N + 127) / 128;   // 391 gemm blocks
constexpr int NW = N / 4;             // 12500 agg blocks
constexpr int T4 = E / 4;             // 200000 scatter threads
constexpr int GF = 3 * GM;            // 1173 = 782 scatter + 391 gemm

// ---------------- Phase A: chunk histograms + per-edge rank + W transpose ---
__global__ __launch_bounds__(1024) void k_hist(const int* __restrict__ col,
                                               unsigned char* __restrict__ hist,
                                               unsigned char* __restrict__ rank,
                                               const float* __restrict__ W1,
                                               const float* __restrict__ W2,
                                               __half* __restrict__ T1,
                                               __half* __restrict__ T2) {
    __shared__ unsigned int h[HWRD];
    int b = blockIdx.x, t = threadIdx.x;
    if (b >= HB) {                        // 32 spare blocks: Wt[n][k]=fp16(W[k][n])
        int o = (b - HB) * 1024 + t;      // 0..32767
        const float* W = (o < 16384) ? W1 : W2;
        __half* T = (o < 16384) ? T1 : T2;
        int oo = o & 16383;
        int n = oo >> 7, k = oo & 127;
        T[oo] = (__half)W[k * 128 + n];
        return;
    }
    for (int i = t; i < HWRD; i += 1024) h[i] = 0;
    __syncthreads();
    int e0 = b * EPB;
    for (int e = e0 + t; e < e0 + EPB; e += 1024) {
        int c = col[e];
        unsigned int old = atomicAdd(&h[c >> 2], 1u << ((c & 3) * 8));
        rank[e] = (unsigned char)((old >> ((c & 3) * 8)) & 0xff);
    }
    __syncthreads();
    unsigned int* out = (unsigned int*)(hist + (size_t)b * 50000);
    for (int i = t; i < HWRD; i += 1024) out[i] = h[i];
}

// ---------------- Phase B: per-node prefix over chunks; deg + dinv ---------
__global__ void k_colscan(unsigned char* __restrict__ hist, int* __restrict__ deg,
                          float* __restrict__ dinv) {
    int c = blockIdx.x * 256 + threadIdx.x;
    if (c >= N) return;
    int sum = 0;
#pragma unroll 4
    for (int b = 0; b < HB; ++b) {
        size_t idx = (size_t)b * 50000 + c;
        int v = hist[idx];
        hist[idx] = (unsigned char)sum;   // exclusive prefix (deg<=255)
        sum += v;
    }
    deg[c] = sum;
    dinv[c] = rsqrtf((float)(sum + 1));   // +1 self loop
}

// ---------------- fp8 helpers (OCP e4m3 on gfx950) ----------------
__device__ __forceinline__ unsigned char f8enc(float v) {
    return (unsigned char)(__builtin_amdgcn_cvt_pk_fp8_f32(v, v, 0, false) & 0xff);
}
__device__ __forceinline__ void add8f8(float* a, uint2 u) {
    f32x2 f0 = __builtin_amdgcn_cvt_pk_f32_fp8(u.x, false);
    f32x2 f1 = __builtin_amdgcn_cvt_pk_f32_fp8(u.x, true);
    f32x2 f2 = __builtin_amdgcn_cvt_pk_f32_fp8(u.y, false);
    f32x2 f3 = __builtin_amdgcn_cvt_pk_f32_fp8(u.y, true);
    a[0] += f0[0]; a[1] += f0[1]; a[2] += f1[0]; a[3] += f1[1];
    a[4] += f2[0]; a[5] += f2[1]; a[6] += f3[0]; a[7] += f3[1];
}

// ---------------- MFMA GEMM: out8[r] = fp8(dinv[r] * (A[r] @ W)) -----------
__device__ __forceinline__ half8 ldA(const float* rowp, int koff) {
    float4 u0 = *(const float4*)(rowp + koff);
    float4 u1 = *(const float4*)(rowp + koff + 4);
    half8 r;
    r[0] = (_Float16)u0.x; r[1] = (_Float16)u0.y;
    r[2] = (_Float16)u0.z; r[3] = (_Float16)u0.w;
    r[4] = (_Float16)u1.x; r[5] = (_Float16)u1.y;
    r[6] = (_Float16)u1.z; r[7] = (_Float16)u1.w;
    return r;
}
__device__ __forceinline__ half8 ldA(const __half* rowp, int koff) {
    return *(const half8*)(rowp + koff);
}

template <typename TA>
__device__ __forceinline__ void mfma_gemm(const TA* __restrict__ A,
                                          const __half* __restrict__ Wt,
                                          const float* __restrict__ dinv,
                                          unsigned char* __restrict__ out8,
                                          int row0, int tid) {
    int wave = tid >> 6, lane = tid & 63;
    int quad = lane >> 4, c16 = lane & 15;
    int m0 = row0 + wave * 32;
    int ra = m0 + c16;      if (ra >= N) ra = 0;   // OOB rows: dummy read row 0
    int rb = m0 + 16 + c16; if (rb >= N) rb = 0;
    const TA* pa = A + (size_t)ra * D;
    const TA* pb = A + (size_t)rb * D;

    f32x4 acc[2][8];
#pragma unroll
    for (int i = 0; i < 2; ++i)
#pragma unroll
        for (int j = 0; j < 8; ++j) acc[i][j] = (f32x4){0.f, 0.f, 0.f, 0.f};

#pragma unroll
    for (int kq = 0; kq < 4; ++kq) {
        int koff = kq * 32 + quad * 8;
        half8 a0 = ldA(pa, koff);
        half8 a1 = ldA(pb, koff);
#pragma unroll
        for (int nt = 0; nt < 8; ++nt) {
            half8 bf = *(const half8*)(Wt + (size_t)(nt * 16 + c16) * D + koff);
            acc[0][nt] = __builtin_amdgcn_mfma_f32_16x16x32_f16(a0, bf, acc[0][nt], 0, 0, 0);
            acc[1][nt] = __builtin_amdgcn_mfma_f32_16x16x32_f16(a1, bf, acc[1][nt], 0, 0, 0);
        }
    }

    // C/D: col = lane&15, row = quad*4 + reg
#pragma unroll
    for (int rt = 0; rt < 2; ++rt) {
        int mt = m0 + rt * 16;
#pragma unroll
        for (int i = 0; i < 4; ++i) {
            int grow = mt + quad * 4 + i;
            if (grow < N) {
                float s = dinv[grow];
                unsigned char* orow = out8 + (size_t)grow * D + c16;
#pragma unroll
                for (int nt = 0; nt < 8; ++nt)
                    orow[nt * 16] = f8enc(acc[rt][nt][i] * s);
            }
        }
    }
}

// ---------------- Phase C fused: parallel rank-scatter + GEMM-1 -------------
__global__ __launch_bounds__(256) void k_fuse(const int* __restrict__ ei,
                                              const unsigned char* __restrict__ hist,
                                              const unsigned char* __restrict__ rank,
                                              unsigned short* __restrict__ csr,
                                              const float* __restrict__ x,
                                              const __half* __restrict__ Wt1,
                                              const float* __restrict__ dinv,
                                              unsigned char* __restrict__ out8) {
    int b = blockIdx.x, m = b % 3;
    if (m < 2) {
        // ---- scatter: fully parallel, slot = pref[chunk][c] + rank[e] ----
        int sb = (b / 3) * 2 + m;
        int t = sb * 256 + threadIdx.x;
        if (t >= T4) return;
#pragma unroll
        for (int i = 0; i < 4; ++i) {
            int e = t + i * T4;
            int c = ei[E + e];
            int r = ei[e];
            int chunk = e / EPB;
            int slot = (int)hist[(size_t)chunk * 50000 + c] + (int)rank[e];
            if (slot < CAP) csr[(c << 6) + slot] = (unsigned short)r;
        }
        return;
    }
    // ---- gemm branch ----
    mfma_gemm<float>(x, Wt1, dinv, out8, (b / 3) * 128, threadIdx.x);
}

// ---------------- GEMM layer 2 (fp16 A -> fp8 out) ----------------
__global__ __launch_bounds__(256) void k_gemm(const __half* __restrict__ A,
                                              const __half* __restrict__ Wt,
                                              const float* __restrict__ dinv,
                                              unsigned char* __restrict__ out8) {
    mfma_gemm<__half>(A, Wt, dinv, out8, blockIdx.x * 128, threadIdx.x);
}

// ---------------- Aggregation core (1 wave/node, fp8 row-sum) --------------
__device__ __forceinline__ float agg_core(int c, int lane,
                                          const unsigned char* __restrict__ hs8,
                                          const int* __restrict__ deg,
                                          const unsigned short* __restrict__ csr,
                                          float* a0) {
    int qw = lane >> 4;         // 0..3: edge within group of 4
    int q  = lane & 15;         // column group: bytes q*8..q*8+7
    int dgRaw = deg[c];
    int dg = dgRaw < CAP ? dgRaw : CAP;
    float dc = rsqrtf((float)(dgRaw + 1));
    int e0 = c << 6;

    float a1[8] = {0, 0, 0, 0, 0, 0, 0, 0};
    float a2[8] = {0, 0, 0, 0, 0, 0, 0, 0};
    float a3[8] = {0, 0, 0, 0, 0, 0, 0, 0};
#pragma unroll
    for (int t = 0; t < 8; ++t) a0[t] = 0.f;
    if (qw == 0)                // self loop (hs8[c] already = dinv[c]*h[c])
        add8f8(a0, *(const uint2*)&hs8[(size_t)c * D + q * 8]);

    int j = 0;
    for (; j + 16 <= dg; j += 16) {
        int r0 = csr[e0 + j + qw];
        int r1 = csr[e0 + j + 4 + qw];
        int r2 = csr[e0 + j + 8 + qw];
        int r3 = csr[e0 + j + 12 + qw];
        uint2 u0 = *(const uint2*)&hs8[(size_t)r0 * D + q * 8];
        uint2 u1 = *(const uint2*)&hs8[(size_t)r1 * D + q * 8];
        uint2 u2 = *(const uint2*)&hs8[(size_t)r2 * D + q * 8];
        uint2 u3 = *(const uint2*)&hs8[(size_t)r3 * D + q * 8];
        add8f8(a0, u0); add8f8(a1, u1); add8f8(a2, u2); add8f8(a3, u3);
    }
    if (j + 8 <= dg) {
        int r0 = csr[e0 + j + qw];
        int r1 = csr[e0 + j + 4 + qw];
        uint2 u0 = *(const uint2*)&hs8[(size_t)r0 * D + q * 8];
        uint2 u1 = *(const uint2*)&hs8[(size_t)r1 * D + q * 8];
        add8f8(a0, u0); add8f8(a1, u1);
        j += 8;
    }
    if (j + 4 <= dg) {
        int r0 = csr[e0 + j + qw];
        add8f8(a0, *(const uint2*)&hs8[(size_t)r0 * D + q * 8]);
        j += 4;
    }
    int rem = dg - j;                     // 0..3
    if (qw < rem) {
        int r0 = csr[e0 + j + qw];
        add8f8(a1, *(const uint2*)&hs8[(size_t)r0 * D + q * 8]);
    }

#pragma unroll
    for (int t = 0; t < 8; ++t) a0[t] += a1[t];
#pragma unroll
    for (int t = 0; t < 8; ++t) a2[t] += a3[t];
#pragma unroll
    for (int t = 0; t < 8; ++t) a0[t] += a2[t];
#pragma unroll
    for (int t = 0; t < 8; ++t) a0[t] += __shfl_xor(a0[t], 16, 64);
#pragma unroll
    for (int t = 0; t < 8; ++t) a0[t] += __shfl_xor(a0[t], 32, 64);
    return dc;
}

// layer-1 agg: writes fp16 rows (coalesced; gemm2 scales its own output)
__global__ __launch_bounds__(256) void k_agg1(const unsigned char* __restrict__ hs8,
                                              const int* __restrict__ deg,
                                              const unsigned short* __restrict__ csr,
                                              const float* __restrict__ bias,
                                              __half* __restrict__ outH) {
    int wave = threadIdx.x >> 6;
    int lane = threadIdx.x & 63;
    int c = blockIdx.x * 4 + wave;
    float a0[8];
    float dc = agg_core(c, lane, hs8, deg, csr, a0);
    if ((lane >> 4) == 0) {
        int q = lane & 15;
        union { __half2 h[4]; uint4 u; } p;
#pragma unroll
        for (int i = 0; i < 4; ++i) {
            float xv = fmaxf(fmaf(dc, a0[2 * i],     bias[q * 8 + 2 * i]),     0.f);
            float yv = fmaxf(fmaf(dc, a0[2 * i + 1], bias[q * 8 + 2 * i + 1]), 0.f);
            p.h[i] = __floats2half2_rn(xv, yv);
        }
        *(uint4*)&outH[(size_t)c * D + q * 8] = p.u;
    }
}

// layer-2 agg: reduces h2 rows straight into per-block pool partials
__global__ __launch_bounds__(256) void k_agg2(const unsigned char* __restrict__ hs8,
                                              const int* __restrict__ deg,
                                              const unsigned short* __restrict__ csr,
                                              const float* __restrict__ bias,
                                              float* __restrict__ gpart) {
    __shared__ float gblk[4][128];
    int wave = threadIdx.x >> 6;
    int lane = threadIdx.x & 63;
    int c = blockIdx.x * 4 + wave;
    float a0[8];
    float dc = agg_core(c, lane, hs8, deg, csr, a0);
    if ((lane >> 4) == 0) {
        int q = lane & 15;
#pragma unroll
        for (int i = 0; i < 8; ++i)
            gblk[wave][q * 8 + i] = fmaxf(fmaf(dc, a0[i], bias[q * 8 + i]), 0.f);
    }
    __syncthreads();
    int t = threadIdx.x;
    if (t < 128)
        gpart[(size_t)blockIdx.x * 128 + t] =
            gblk[0][t] + gblk[1][t] + gblk[2][t] + gblk[3][t];
}

// ---------------- Pool stage 2: 12500 partials -> 256 partials --------------
__global__ __launch_bounds__(256) void k_pool(const float* __restrict__ gpart,
                                              float* __restrict__ gpart2) {
    int d = threadIdx.x & 127;
    int half = threadIdx.x >> 7;
    int b = blockIdx.x;                 // 256 blocks
    int per = (NW + 255) / 256;         // 49
    int r0 = b * per;
    int r1 = r0 + per;
    if (r1 > NW) r1 = NW;
    float acc = 0.f;
    for (int r = r0 + half; r < r1; r += 2)
        acc += gpart[(size_t)r * D + d];
    __shared__ float red[256];
    red[threadIdx.x] = acc;
    __syncthreads();
    if (half == 0) gpart2[(size_t)b * D + d] = red[d] + red[128 + d];
}

// ---------------- Final: g = sum(gpart2)/N; out = g@Wc + bc ----------------
__global__ __launch_bounds__(512) void k_final(const float* __restrict__ gpart2,
                                               const float* __restrict__ Wc,
                                               const float* __restrict__ bc,
                                               float* __restrict__ out) {
    __shared__ float g[D];
    __shared__ float red[512];
    int t = threadIdx.x;
    int d = t & 127, grp = t >> 7;
    float s = 0.f;
#pragma unroll 4
    for (int w = grp * 64; w < grp * 64 + 64; ++w)
        s += gpart2[(size_t)w * D + d];
    red[t] = s;
    __syncthreads();
    if (grp == 0)
        g[d] = (red[d] + red[128 + d] + red[256 + d] + red[384 + d]) * (1.0f / (float)N);
    __syncthreads();
    if (t < DOUT) {
        float acc = bc[t];
        for (int dd = 0; dd < D; ++dd) acc = fmaf(g[dd], Wc[dd * DOUT + t], acc);
        out[t] = acc;
    }
}

extern "C" void kernel_launch(void* const* d_in, const int* in_sizes, int n_in,
                              void* d_out, int out_size, void* d_ws, size_t ws_size,
                              hipStream_t stream) {
    const float* x  = (const float*)d_in[0];
    const int*   ei = (const int*)d_in[1];
    const float* W1 = (const float*)d_in[2];
    const float* b1 = (const float*)d_in[3];
    const float* W2 = (const float*)d_in[4];
    const float* b2 = (const float*)d_in[5];
    const float* Wc = (const float*)d_in[6];
    const float* bc = (const float*)d_in[7];
    float* out = (float*)d_out;

    char* ws = (char*)d_ws;
    size_t off = 0;
    auto alloc = [&](size_t bytes) {
        void* p = ws + off;
        off += (bytes + 511) & ~(size_t)511;
        return p;
    };
    unsigned char*  hist   = (unsigned char*) alloc((size_t)HB * 50000);     // 6.4MB
    unsigned char*  rank   = (unsigned char*) alloc((size_t)E);              // 0.8MB
    int*            deg    = (int*)           alloc((size_t)N * 4);
    float*          dinv   = (float*)         alloc((size_t)N * 4);
    unsigned short* csr    = (unsigned short*)alloc((size_t)N * CAP * 2);    // 6.4MB
    unsigned char*  hs8    = (unsigned char*) alloc((size_t)N * D);          // 6.4MB
    __half*         hactH  = (__half*)        alloc((size_t)N * D * 2);      // 12.8MB
    __half*         Wt1    = (__half*)        alloc((size_t)D * D * 2);      // 32KB
    __half*         Wt2    = (__half*)        alloc((size_t)D * D * 2);      // 32KB
    float*          gpart  = (float*)         alloc((size_t)NW * D * 4);     // 6.4MB
    float*          gpart2 = (float*)         alloc((size_t)256 * D * 4);
    (void)ws_size; (void)in_sizes; (void)n_in; (void)out_size;

    const int* col = ei + E;

    // Phase A: histograms + ranks + W transposes (one dispatch)
    k_hist<<<HB + 32, 1024, 0, stream>>>(col, hist, rank, W1, W2, Wt1, Wt2);
    // Phase B: per-node prefix; deg/dinv
    k_colscan<<<(N + 255) / 256, 256, 0, stream>>>(hist, deg, dinv);
    // Phase C: parallel scatter (2/3) + MFMA gemm layer 1 (1/3) -> fp8 rows
    k_fuse<<<GF, 256, 0, stream>>>(ei, hist, rank, csr, x, Wt1, dinv, hs8);

    k_agg1<<<NW, 256, 0, stream>>>(hs8, deg, csr, b1, hactH);
    k_gemm<<<GM, 256, 0, stream>>>(hactH, Wt2, dinv, hs8);
    k_agg2<<<NW, 256, 0, stream>>>(hs8, deg, csr, b2, gpart);
    k_pool<<<256, 256, 0, stream>>>(gpart, gpart2);
    k_final<<<1, 512, 0, stream>>>(gpart2, Wc, bc, out);
}